// Round 17
// baseline (197.084 us; speedup 1.0000x reference)
//
#include <hip/hip_runtime.h>
#include <hip/hip_bf16.h>
#include <cstdint>

#define B_SZ 8
#define NPTS 4096
#define KNN  20
#define NTOT (B_SZ * NPTS)   // 32768 points
#define PPB  8               // points per edge-kernel block
#define NPREP 1093           // prep blocks (1024 u + 64 W3 + 4 W2 + 1 gzero)

typedef unsigned int uint;
typedef unsigned short ushort;
using short8 = __attribute__((ext_vector_type(8))) short;
using f32x4  = __attribute__((ext_vector_type(4))) float;

__device__ __forceinline__ ushort f2bf(float f) {
  uint u = __float_as_uint(f);
  u += 0x7fff + ((u >> 16) & 1);          // RNE
  return (ushort)(u >> 16);
}
__device__ __forceinline__ float bf2f(ushort h) {
  return __uint_as_float(((uint)h) << 16);
}
// order-monotone float<->uint encoding (exact; for atomicMax-based max)
__device__ __forceinline__ uint fenc(float f) {
  uint u = __float_as_uint(f);
  return (u & 0x80000000u) ? ~u : (u | 0x80000000u);
}
__device__ __forceinline__ float fdec(uint e) {
  uint u = (e & 0x80000000u) ? (e & 0x7fffffffu) : ~e;
  return __uint_as_float(u);
}

// ---------- kNN helpers ----------
__device__ __forceinline__ void sortf64x2(float& v0, float& v1, int lane) {
  // two independent 64-lane bitonic sorts, interleaved for ILP
  #pragma unroll
  for (int k = 2; k <= 64; k <<= 1) {
    #pragma unroll
    for (int j = k >> 1; j > 0; j >>= 1) {
      float o0 = __shfl_xor(v0, j, 64);
      float o1 = __shfl_xor(v1, j, 64);
      bool keepmin = (((lane & k) == 0) == ((lane & j) == 0));
      bool lt0 = v0 < o0; v0 = (keepmin == lt0) ? v0 : o0;
      bool lt1 = v1 < o1; v1 = (keepmin == lt1) ? v1 : o1;
    }
  }
}

__device__ __forceinline__ void sortu64x2(unsigned long long& v0,
                                          unsigned long long& v1, int lane) {
  #pragma unroll
  for (int k = 2; k <= 64; k <<= 1) {
    #pragma unroll
    for (int j = k >> 1; j > 0; j >>= 1) {
      unsigned long long o0 = __shfl_xor(v0, j, 64);
      unsigned long long o1 = __shfl_xor(v1, j, 64);
      bool keepmin = (((lane & k) == 0) == ((lane & j) == 0));
      bool lt0 = v0 < o0; v0 = (keepmin == lt0) ? v0 : o0;
      bool lt1 = v1 < o1; v1 = (keepmin == lt1) ? v1 : o1;
    }
  }
}

// ---------- K1: prep (blocks [0,NPREP)) + kNN 2-rows-per-wave (rest) ----------
// R16 established: knn pins at ~16 waves/CU, 49% VALUBusy regardless of
// launch_bounds -> latency-bound on dependent cross-lane chains. Fix via ILP:
// each wave handles TWO rows of the same batch (x loads shared; sorts/scans
// pairwise-interleaved). Wave count halves; per-wave issue ~doubles.
__global__ void knn_prep_kernel(
    const float* __restrict__ x,  const float* __restrict__ W1,
    const float* __restrict__ W3, const float* __restrict__ W2,
    ushort* __restrict__ u, ushort* __restrict__ W3b, ushort* __restrict__ W2b,
    uint* __restrict__ g_enc, int* __restrict__ idx_out) {
  __shared__ int surv[8][256];      // 8 KB (knn path only; 2 segs per wave)
  __shared__ int cnt[8];

  if (blockIdx.x < NPREP) {         // ---- prep path ----
    int blk = blockIdx.x;
    if (blk < 1024) {
      int t = blk * 256 + threadIdx.x;      // 262144 total
      int p = t >> 3, c0 = (t & 7) * 8;
      int b = p >> 12, n = p & (NPTS - 1);
      const float* xb = x + (size_t)b * 3 * NPTS;
      float x0 = xb[n], x1 = xb[NPTS + n], x2 = xb[2 * NPTS + n];
      uint pk[4];
      #pragma unroll
      for (int j = 0; j < 8; ++j) {
        const float* w = W1 + (c0 + j) * 6;
        float v = w[3] * x0 + w[4] * x1 + w[5] * x2;
        ushort h = f2bf(v);
        if (j & 1) pk[j >> 1] |= ((uint)h << 16); else pk[j >> 1] = h;
      }
      uint4 q; q.x = pk[0]; q.y = pk[1]; q.z = pk[2]; q.w = pk[3];
      *reinterpret_cast<uint4*>(u + (size_t)p * 64 + c0) = q;
    } else if (blk < 1088) {
      int t = (blk - 1024) * 256 + threadIdx.x;   // W3 cast
      const float4* src = reinterpret_cast<const float4*>(W3 + t * 8);
      float4 f0 = src[0], f1 = src[1];
      uint4 pk;
      pk.x = (uint)f2bf(f0.x) | ((uint)f2bf(f0.y) << 16);
      pk.y = (uint)f2bf(f0.z) | ((uint)f2bf(f0.w) << 16);
      pk.z = (uint)f2bf(f1.x) | ((uint)f2bf(f1.y) << 16);
      pk.w = (uint)f2bf(f1.z) | ((uint)f2bf(f1.w) << 16);
      *reinterpret_cast<uint4*>(W3b + t * 8) = pk;
    } else if (blk < 1092) {
      int t = (blk - 1088) * 256 + threadIdx.x;   // W2 cast
      const float4* src = reinterpret_cast<const float4*>(W2 + t * 8);
      float4 f0 = src[0], f1 = src[1];
      uint4 pk;
      pk.x = (uint)f2bf(f0.x) | ((uint)f2bf(f0.y) << 16);
      pk.y = (uint)f2bf(f0.z) | ((uint)f2bf(f0.w) << 16);
      pk.z = (uint)f2bf(f1.x) | ((uint)f2bf(f1.y) << 16);
      pk.w = (uint)f2bf(f1.z) | ((uint)f2bf(f1.w) << 16);
      *reinterpret_cast<uint4*>(W2b + t * 8) = pk;
    } else {
      for (int i = threadIdx.x; i < B_SZ * 1024; i += 256) g_enc[i] = 0;
    }
    return;
  }

  // ---- knn path: wave w owns rows row0, row0+1 (same batch) ----
  const unsigned long long INFK = ~0ull;
  int w = threadIdx.x >> 6, lane = threadIdx.x & 63;
  int row0 = ((blockIdx.x - NPREP) * 4 + w) * 2;   // blocks of 8 rows, batch-aligned
  int b = row0 >> 12;
  int n0 = row0 & (NPTS - 1), n1 = n0 + 1;
  const float* xb = x + (size_t)b * 3 * NPTS;
  float q0x = xb[n0], q0y = xb[NPTS + n0], q0z = xb[2 * NPTS + n0];
  float q1x = xb[n1], q1y = xb[NPTS + n1], q1z = xb[2 * NPTS + n1];
  if (lane == 0) { cnt[2 * w] = 0; cnt[2 * w + 1] = 0; }

  const float4* X0 = reinterpret_cast<const float4*>(xb);
  const float4* X1 = reinterpret_cast<const float4*>(xb + NPTS);
  const float4* X2 = reinterpret_cast<const float4*>(xb + 2 * NPTS);

  // pass A: shared x loads, two key sets
  uint kregA[32], kregB[32];
  float bm0 = 3.0e38f, bm1 = 3.0e38f;
  #pragma unroll
  for (int i = 0; i < 16; ++i) {
    int v4 = i * 64 + lane;
    float4 a0 = X0[v4], a1 = X1[v4], a2 = X2[v4];
    float dx, dy, dz, d0, d1, d2, d3;
    // row0
    dx = a0.x - q0x; dy = a1.x - q0y; dz = a2.x - q0z; d0 = dx*dx + dy*dy + dz*dz;
    dx = a0.y - q0x; dy = a1.y - q0y; dz = a2.y - q0z; d1 = dx*dx + dy*dy + dz*dz;
    dx = a0.z - q0x; dy = a1.z - q0y; dz = a2.z - q0z; d2 = dx*dx + dy*dy + dz*dz;
    dx = a0.w - q0x; dy = a1.w - q0y; dz = a2.w - q0z; d3 = dx*dx + dy*dy + dz*dz;
    bm0 = fminf(bm0, fminf(fminf(d0, d1), fminf(d2, d3)));
    kregA[2*i]   = (__float_as_uint(d0) >> 16) | (__float_as_uint(d1) & 0xFFFF0000u);
    kregA[2*i+1] = (__float_as_uint(d2) >> 16) | (__float_as_uint(d3) & 0xFFFF0000u);
    // row1 (same a0/a1/a2)
    dx = a0.x - q1x; dy = a1.x - q1y; dz = a2.x - q1z; d0 = dx*dx + dy*dy + dz*dz;
    dx = a0.y - q1x; dy = a1.y - q1y; dz = a2.y - q1z; d1 = dx*dx + dy*dy + dz*dz;
    dx = a0.z - q1x; dy = a1.z - q1y; dz = a2.z - q1z; d2 = dx*dx + dy*dy + dz*dz;
    dx = a0.w - q1x; dy = a1.w - q1y; dz = a2.w - q1z; d3 = dx*dx + dy*dy + dz*dz;
    bm1 = fminf(bm1, fminf(fminf(d0, d1), fminf(d2, d3)));
    kregB[2*i]   = (__float_as_uint(d0) >> 16) | (__float_as_uint(d1) & 0xFFFF0000u);
    kregB[2*i+1] = (__float_as_uint(d2) >> 16) | (__float_as_uint(d3) & 0xFFFF0000u);
  }

  // thresholds (interleaved sorts)
  sortf64x2(bm0, bm1, lane);
  float T0 = __shfl(bm0, 19, 64), T1 = __shfl(bm1, 19, 64);
  uint T016 = __float_as_uint(T0) >> 16, T116 = __float_as_uint(T1) >> 16;

  // pass B: filter both rows, append to own segments
  asm volatile("s_waitcnt lgkmcnt(0)" ::: "memory");
  #pragma unroll
  for (int i = 0; i < 16; ++i) {
    int m0 = (i * 64 + lane) * 4;
    uint ka = kregA[2*i], kb = kregA[2*i+1];
    if ((ka & 0xffffu) <= T016) { int s = atomicAdd(&cnt[2*w], 1); if (s < 256) surv[2*w][s] = m0; }
    if ((ka >> 16)     <= T016) { int s = atomicAdd(&cnt[2*w], 1); if (s < 256) surv[2*w][s] = m0 + 1; }
    if ((kb & 0xffffu) <= T016) { int s = atomicAdd(&cnt[2*w], 1); if (s < 256) surv[2*w][s] = m0 + 2; }
    if ((kb >> 16)     <= T016) { int s = atomicAdd(&cnt[2*w], 1); if (s < 256) surv[2*w][s] = m0 + 3; }
    uint kc = kregB[2*i], kd = kregB[2*i+1];
    if ((kc & 0xffffu) <= T116) { int s = atomicAdd(&cnt[2*w+1], 1); if (s < 256) surv[2*w+1][s] = m0; }
    if ((kc >> 16)     <= T116) { int s = atomicAdd(&cnt[2*w+1], 1); if (s < 256) surv[2*w+1][s] = m0 + 1; }
    if ((kd & 0xffffu) <= T116) { int s = atomicAdd(&cnt[2*w+1], 1); if (s < 256) surv[2*w+1][s] = m0 + 2; }
    if ((kd >> 16)     <= T116) { int s = atomicAdd(&cnt[2*w+1], 1); if (s < 256) surv[2*w+1][s] = m0 + 3; }
  }
  asm volatile("s_waitcnt lgkmcnt(0)" ::: "memory");
  int M0 = cnt[2*w], M1 = cnt[2*w+1];

  { // interleaved chunked-bitonic fast path (discarded for any row with M>256)
    int M0c = M0 <= 256 ? M0 : 0, M1c = M1 <= 256 ? M1 : 0;
    int nch = ((M0c > M1c ? M0c : M1c) + 63) >> 6;
    unsigned long long run0 = INFK, run1 = INFK;
    for (int c = 0; c < nch; ++c) {
      int s = c * 64 + lane;
      unsigned long long v0 = INFK, v1 = INFK;
      if (s < M0c) {
        int m = surv[2*w][s];
        float dx = xb[m] - q0x, dy = xb[NPTS + m] - q0y, dz = xb[2 * NPTS + m] - q0z;
        float d = dx * dx + dy * dy + dz * dz;
        v0 = ((unsigned long long)__float_as_uint(d) << 32) | (unsigned)m;
      }
      if (s < M1c) {
        int m = surv[2*w+1][s];
        float dx = xb[m] - q1x, dy = xb[NPTS + m] - q1y, dz = xb[2 * NPTS + m] - q1z;
        float d = dx * dx + dy * dy + dz * dz;
        v1 = ((unsigned long long)__float_as_uint(d) << 32) | (unsigned)m;
      }
      sortu64x2(v0, v1, lane);
      if (c == 0) {
        run0 = v0; run1 = v1;
      } else {
        unsigned long long b0 = __shfl(v0, (19 - lane) & 63, 64);
        unsigned long long b1 = __shfl(v1, (19 - lane) & 63, 64);
        unsigned long long c0 = run0 < b0 ? run0 : b0;
        unsigned long long c1 = run1 < b1 ? run1 : b1;
        run0 = (lane < KNN) ? c0 : INFK;
        run1 = (lane < KNN) ? c1 : INFK;
        sortu64x2(run0, run1, lane);
      }
    }
    if (M0 <= 256 && lane < KNN)
      idx_out[(size_t)row0 * KNN + lane] = (int)(run0 & 0xFFFFFFFFull);
    if (M1 <= 256 && lane < KNN)
      idx_out[(size_t)(row0 + 1) * KNN + lane] = (int)(run1 & 0xFFFFFFFFull);
  }

  // pathological fallback per row (tie storms only): threshold-free extraction
  #pragma unroll 1
  for (int rr = 0; rr < 2; ++rr) {
    int M = rr ? M1 : M0;
    if (M <= 256) continue;
    float qx = rr ? q1x : q0x, qy = rr ? q1y : q0y, qz = rr ? q1z : q0z;
    int row = row0 + rr;
    unsigned long long prev = 0ull;
    for (int r = 0; r < KNN; ++r) {
      unsigned long long best = INFK;
      for (int i = 0; i < 16; ++i) {
        int v4 = i * 64 + lane;
        float4 a0 = X0[v4], a1 = X1[v4], a2 = X2[v4];
        float dx, dy, dz, d[4];
        dx = a0.x - qx; dy = a1.x - qy; dz = a2.x - qz; d[0] = dx*dx + dy*dy + dz*dz;
        dx = a0.y - qx; dy = a1.y - qy; dz = a2.y - qz; d[1] = dx*dx + dy*dy + dz*dz;
        dx = a0.z - qx; dy = a1.z - qy; dz = a2.z - qz; d[2] = dx*dx + dy*dy + dz*dz;
        dx = a0.w - qx; dy = a1.w - qy; dz = a2.w - qz; d[3] = dx*dx + dy*dy + dz*dz;
        #pragma unroll
        for (int j = 0; j < 4; ++j) {
          int m = i * 256 + lane * 4 + j;
          unsigned long long key =
              ((unsigned long long)__float_as_uint(d[j]) << 32) | (unsigned)m;
          if ((r == 0 || key > prev) && key < best) best = key;
        }
      }
      #pragma unroll
      for (int off = 32; off; off >>= 1) {
        unsigned long long o = __shfl_xor(best, off, 64);
        best = o < best ? o : best;
      }
      if (lane == 0) idx_out[(size_t)row * KNN + r] = (int)(best & 0xFFFFFFFFull);
      prev = best;
    }
  }
}

// ---------- K2: edge conv via MFMA, bf16 h128 output ----------
__global__ __launch_bounds__(256, 4) void edge_kernel(
    const float* __restrict__ x,  const float* __restrict__ W1, const float* __restrict__ b1,
    const ushort* __restrict__ W2b, const float* __restrict__ b2,
    const ushort* __restrict__ u, const int* __restrict__ idx,
    ushort* __restrict__ h128b) {
  __shared__ __align__(16) char h1s[PPB * 32 * 128];     // 32 KB
  __shared__ float vs[PPB * 64];                         // 2 KB
  __shared__ int   nbs[PPB * KNN];

  int tid = threadIdx.x, w = tid >> 6, l = tid & 63;
  int p0 = blockIdx.x * PPB;
  int b = p0 >> 12;
  const float* xb = x + (size_t)b * 3 * NPTS;

  for (int t = tid; t < PPB * 64; t += 256) {
    int p = t >> 6, c = t & 63;
    int n = (p0 + p) & (NPTS - 1);
    float x0 = xb[n], x1 = xb[NPTS + n], x2 = xb[2 * NPTS + n];
    const float* wr = W1 + c * 6;
    vs[t] = (wr[0] - wr[3]) * x0 + (wr[1] - wr[4]) * x1 + (wr[2] - wr[5]) * x2 + b1[c];
  }
  if (tid < PPB * KNN) nbs[tid] = idx[(size_t)p0 * KNN + tid];

  short8 bfr[8][2];
  #pragma unroll
  for (int nt = 0; nt < 8; ++nt) {
    #pragma unroll
    for (int ks = 0; ks < 2; ++ks) {
      bfr[nt][ks] = *(const short8*)(W2b + (nt * 16 + (l & 15)) * 64
                                         + ks * 32 + (l >> 4) * 8);
    }
  }
  __syncthreads();

  const ushort* ub = u + (((size_t)b) << 12) * 64;
  #pragma unroll
  for (int j = 0; j < 8; ++j) {
    int e_loc = j * 8 + (l >> 3);
    int p_loc = (w << 1) + (e_loc >> 5);
    int e_in = e_loc & 31;
    int e_src = (e_in < KNN) ? e_in : e_in - KNN;
    int nb = nbs[p_loc * KNN + e_src];
    int c0 = (l & 7) * 8;
    uint4 uv = *(const uint4*)(ub + (((size_t)nb) << 6) + c0);
    const float* vp = vs + p_loc * 64 + c0;
    float4 v0 = *(const float4*)vp, v1 = *(const float4*)(vp + 4);
    float h0 = fmaxf(bf2f((ushort)(uv.x & 0xffff)) + v0.x, 0.f);
    float h1 = fmaxf(bf2f((ushort)(uv.x >> 16))    + v0.y, 0.f);
    float h2 = fmaxf(bf2f((ushort)(uv.y & 0xffff)) + v0.z, 0.f);
    float h3 = fmaxf(bf2f((ushort)(uv.y >> 16))    + v0.w, 0.f);
    float h4 = fmaxf(bf2f((ushort)(uv.z & 0xffff)) + v1.x, 0.f);
    float h5 = fmaxf(bf2f((ushort)(uv.z >> 16))    + v1.y, 0.f);
    float h6 = fmaxf(bf2f((ushort)(uv.w & 0xffff)) + v1.z, 0.f);
    float h7 = fmaxf(bf2f((ushort)(uv.w >> 16))    + v1.w, 0.f);
    uint4 pk;
    pk.x = (uint)f2bf(h0) | ((uint)f2bf(h1) << 16);
    pk.y = (uint)f2bf(h2) | ((uint)f2bf(h3) << 16);
    pk.z = (uint)f2bf(h4) | ((uint)f2bf(h5) << 16);
    pk.w = (uint)f2bf(h6) | ((uint)f2bf(h7) << 16);
    int row = (w << 6) + e_loc;
    int byte = (row * 128 + c0 * 2) ^ ((row & 7) << 4);
    *(uint4*)(h1s + byte) = pk;
  }
  __syncthreads();

  float bias0 = b2[l], bias1 = b2[64 + l];

  #pragma unroll
  for (int pt = 0; pt < 2; ++pt) {
    int rbase = (w << 6) + (pt << 5);
    short8 a[2][2];
    #pragma unroll
    for (int m = 0; m < 2; ++m) {
      #pragma unroll
      for (int ks = 0; ks < 2; ++ks) {
        int row = rbase + m * 16 + (l & 15);
        int byte = (row * 128 + ks * 64 + (l >> 4) * 16) ^ ((row & 7) << 4);
        a[m][ks] = *(const short8*)(h1s + byte);
      }
    }
    float r03 = 0.f, r47 = 0.f;
    #pragma unroll
    for (int nt = 0; nt < 8; ++nt) {
      f32x4 acc0 = {0.f, 0.f, 0.f, 0.f}, acc1 = {0.f, 0.f, 0.f, 0.f};
      acc0 = __builtin_amdgcn_mfma_f32_16x16x32_bf16(a[0][0], bfr[nt][0], acc0, 0, 0, 0);
      acc0 = __builtin_amdgcn_mfma_f32_16x16x32_bf16(a[0][1], bfr[nt][1], acc0, 0, 0, 0);
      acc1 = __builtin_amdgcn_mfma_f32_16x16x32_bf16(a[1][0], bfr[nt][0], acc1, 0, 0, 0);
      acc1 = __builtin_amdgcn_mfma_f32_16x16x32_bf16(a[1][1], bfr[nt][1], acc1, 0, 0, 0);
      float m0 = fmaxf(fmaxf(fmaxf(acc0[0], acc1[0]), fmaxf(acc0[1], acc1[1])),
                       fmaxf(fmaxf(acc0[2], acc1[2]), fmaxf(acc0[3], acc1[3])));
      m0 = fmaxf(m0, __shfl_xor(m0, 16, 64));
      m0 = fmaxf(m0, __shfl_xor(m0, 32, 64));
      if ((l >> 4) == (nt & 3)) { if (nt < 4) r03 = m0; else r47 = m0; }
    }
    int pg = p0 + (w << 1) + pt;
    h128b[(size_t)pg * 128 + l]      = f2bf(fmaxf(r03 + bias0, 0.f));
    h128b[(size_t)pg * 128 + 64 + l] = f2bf(fmaxf(r47 + bias1, 0.f));
  }
}

// ---------- K3: inter via MFMA, 64-point chunks, atomicMax into encoded g ----------
__global__ __launch_bounds__(256, 2) void inter_kernel(
    const ushort* __restrict__ h128b, const ushort* __restrict__ W3b,
    uint* __restrict__ g_enc) {
  __shared__ __align__(16) char as_[64 * 256];   // 16 KB
  int tid = threadIdx.x, w = tid >> 6, l = tid & 63;
  int chunk = blockIdx.x;                         // 0..511 (64 points each)
  const ushort* hp = h128b + (size_t)chunk * 64 * 128;

  { // stage: thread t -> row t>>2, quarter t&3 (64B = 4 uint4)
    int row = tid >> 2, q = tid & 3;
    const uint4* src = reinterpret_cast<const uint4*>(hp + row * 128 + q * 32);
    int sw = (row & 7) << 4;
    int base = row * 256 + q * 64;
    #pragma unroll
    for (int k = 0; k < 4; ++k)
      *(uint4*)(as_ + ((base + k * 16) ^ sw)) = src[k];
  }
  __syncthreads();

  short8 a[4][4];
  #pragma unroll
  for (int m = 0; m < 4; ++m) {
    #pragma unroll
    for (int ks = 0; ks < 4; ++ks) {
      int row = m * 16 + (l & 15);
      int byte = (row * 256 + ks * 64 + (l >> 4) * 16) ^ ((row & 7) << 4);
      a[m][ks] = *(const short8*)(as_ + byte);
    }
  }

  const ushort* wb = W3b + (size_t)(w * 256) * 128;
  float res[4];
  #pragma unroll
  for (int nt = 0; nt < 16; ++nt) {
    f32x4 acc0 = {0.f,0.f,0.f,0.f}, acc1 = {0.f,0.f,0.f,0.f};
    f32x4 acc2 = {0.f,0.f,0.f,0.f}, acc3 = {0.f,0.f,0.f,0.f};
    #pragma unroll
    for (int ks = 0; ks < 4; ++ks) {
      short8 bf = *(const short8*)(wb + (size_t)(nt * 16 + (l & 15)) * 128
                                      + ks * 32 + (l >> 4) * 8);
      acc0 = __builtin_amdgcn_mfma_f32_16x16x32_bf16(a[0][ks], bf, acc0, 0, 0, 0);
      acc1 = __builtin_amdgcn_mfma_f32_16x16x32_bf16(a[1][ks], bf, acc1, 0, 0, 0);
      acc2 = __builtin_amdgcn_mfma_f32_16x16x32_bf16(a[2][ks], bf, acc2, 0, 0, 0);
      acc3 = __builtin_amdgcn_mfma_f32_16x16x32_bf16(a[3][ks], bf, acc3, 0, 0, 0);
    }
    float m01 = fmaxf(fmaxf(fmaxf(acc0[0], acc1[0]), fmaxf(acc0[1], acc1[1])),
                      fmaxf(fmaxf(acc0[2], acc1[2]), fmaxf(acc0[3], acc1[3])));
    float m23 = fmaxf(fmaxf(fmaxf(acc2[0], acc3[0]), fmaxf(acc2[1], acc3[1])),
                      fmaxf(fmaxf(acc2[2], acc3[2]), fmaxf(acc2[3], acc3[3])));
    float m0 = fmaxf(m01, m23);
    m0 = fmaxf(m0, __shfl_xor(m0, 16, 64));
    m0 = fmaxf(m0, __shfl_xor(m0, 32, 64));
    if ((l >> 4) == (nt & 3)) res[nt >> 2] = m0;
  }
  uint* ge = g_enc + (size_t)(chunk >> 6) * 1024 + w * 256;
  #pragma unroll
  for (int g = 0; g < 4; ++g) atomicMax(ge + g * 64 + l, fenc(res[g]));
}

// ---------- K4/5/6: small FCs, one wave per output ----------
__global__ __launch_bounds__(64) void fc_kernel(const float* __restrict__ in,
                                                const uint* __restrict__ enc,
                                                const float* __restrict__ pre_b,
                                                const float* __restrict__ W,
                                                const float* __restrict__ bias,
                                                float* __restrict__ out,
                                                int in_dim, int out_dim, int mode) {
  int blk = blockIdx.x;
  int b = blk / out_dim, o = blk % out_dim;
  int lane = threadIdx.x;
  const float* w = W + (size_t)o * in_dim;
  float s = 0.f;
  for (int c = lane; c < in_dim; c += 64) {
    float v;
    if (mode == 2) v = fmaxf(fdec(enc[(size_t)b * in_dim + c]) + pre_b[c], 0.f);
    else           v = in[(size_t)b * in_dim + c];
    s += v * w[c];
  }
  #pragma unroll
  for (int off = 32; off; off >>= 1) s += __shfl_down(s, off);
  if (lane == 0) {
    float r = s + bias[o];
    if (mode != 1) r = fmaxf(r, 0.0f);
    else if (o == 0 || o == 4 || o == 8) r += 1.0f;
    out[blk] = r;
  }
}

extern "C" void kernel_launch(void* const* d_in, const int* in_sizes, int n_in,
                              void* d_out, int out_size, void* d_ws, size_t ws_size,
                              hipStream_t stream) {
  const float* x  = (const float*)d_in[0];
  const float* W1 = (const float*)d_in[1];
  const float* b1 = (const float*)d_in[2];
  const float* W2 = (const float*)d_in[3];
  const float* b2 = (const float*)d_in[4];
  const float* W3 = (const float*)d_in[5];
  const float* b3 = (const float*)d_in[6];
  const float* W4 = (const float*)d_in[7];
  const float* b4 = (const float*)d_in[8];
  const float* W5 = (const float*)d_in[9];
  const float* b5 = (const float*)d_in[10];
  const float* W6 = (const float*)d_in[11];
  const float* b6 = (const float*)d_in[12];
  float* out = (float*)d_out;

  char* ws = (char*)d_ws;
  ushort* u_bf  = (ushort*)(ws);                              // [0,4M)
  int*    idxb  = (int*)  (ws + (8u  << 20));                 // [8,10.5M)
  ushort* h128b = (ushort*)(ws + (11u << 20));                // [11,19M) bf16
  ushort* W3b   = (ushort*)(ws + (27u << 20));                // 256 KB
  ushort* W2b   = (ushort*)(ws + (27u << 20) + (256u << 10)); // 16 KB
  uint*   g_enc = (uint*) (ws + (5u  << 20));                 // 32 KB
  float*  g4    = (float*)(ws + (6u  << 20));
  float*  g5    = (float*)(ws + (7u  << 20));

  hipLaunchKernelGGL(knn_prep_kernel, dim3(NPREP + 4096), dim3(256), 0, stream,
                     x, W1, W3, W2, u_bf, W3b, W2b, g_enc, idxb);
  hipLaunchKernelGGL(edge_kernel, dim3(NTOT / PPB), dim3(256), 0, stream,
                     x, W1, b1, W2b, b2, u_bf, idxb, h128b);
  hipLaunchKernelGGL(inter_kernel, dim3(512), dim3(256), 0, stream, h128b, W3b, g_enc);
  hipLaunchKernelGGL(fc_kernel, dim3(B_SZ * 512), dim3(64), 0, stream,
                     nullptr, g_enc, b3, W4, b4, g4, 1024, 512, 2);
  hipLaunchKernelGGL(fc_kernel, dim3(B_SZ * 256), dim3(64), 0, stream,
                     g4, nullptr, nullptr, W5, b5, g5, 512, 256, 0);
  hipLaunchKernelGGL(fc_kernel, dim3(B_SZ * 9),   dim3(64), 0, stream,
                     g5, nullptr, nullptr, W6, b6, out, 256, 9, 1);
}

// Round 18
// 185.945 us; speedup vs baseline: 1.0599x; 1.0599x over previous
//
#include <hip/hip_runtime.h>
#include <hip/hip_bf16.h>
#include <cstdint>

#define B_SZ 8
#define NPTS 4096
#define KNN  20
#define NTOT (B_SZ * NPTS)   // 32768 points
#define PPB  8               // points per edge-kernel block
#define NPREP 1093           // prep blocks (1024 u + 64 W3 + 4 W2 + 1 gzero)

typedef unsigned int uint;
typedef unsigned short ushort;
using short8 = __attribute__((ext_vector_type(8))) short;
using f32x4  = __attribute__((ext_vector_type(4))) float;

__device__ __forceinline__ ushort f2bf(float f) {
  uint u = __float_as_uint(f);
  u += 0x7fff + ((u >> 16) & 1);          // RNE
  return (ushort)(u >> 16);
}
__device__ __forceinline__ float bf2f(ushort h) {
  return __uint_as_float(((uint)h) << 16);
}
// order-monotone float<->uint encoding (exact; for atomicMax-based max)
__device__ __forceinline__ uint fenc(float f) {
  uint u = __float_as_uint(f);
  return (u & 0x80000000u) ? ~u : (u | 0x80000000u);
}
__device__ __forceinline__ float fdec(uint e) {
  uint u = (e & 0x80000000u) ? (e & 0x7fffffffu) : ~e;
  return __uint_as_float(u);
}

// ---------- kNN helpers ----------
__device__ __forceinline__ void sortf64x2(float& v0, float& v1, int lane) {
  // two independent 64-lane bitonic sorts, interleaved for ILP
  #pragma unroll
  for (int k = 2; k <= 64; k <<= 1) {
    #pragma unroll
    for (int j = k >> 1; j > 0; j >>= 1) {
      float o0 = __shfl_xor(v0, j, 64);
      float o1 = __shfl_xor(v1, j, 64);
      bool keepmin = (((lane & k) == 0) == ((lane & j) == 0));
      bool lt0 = v0 < o0; v0 = (keepmin == lt0) ? v0 : o0;
      bool lt1 = v1 < o1; v1 = (keepmin == lt1) ? v1 : o1;
    }
  }
}

__device__ __forceinline__ void sortu64x2(unsigned long long& v0,
                                          unsigned long long& v1, int lane) {
  #pragma unroll
  for (int k = 2; k <= 64; k <<= 1) {
    #pragma unroll
    for (int j = k >> 1; j > 0; j >>= 1) {
      unsigned long long o0 = __shfl_xor(v0, j, 64);
      unsigned long long o1 = __shfl_xor(v1, j, 64);
      bool keepmin = (((lane & k) == 0) == ((lane & j) == 0));
      bool lt0 = v0 < o0; v0 = (keepmin == lt0) ? v0 : o0;
      bool lt1 = v1 < o1; v1 = (keepmin == lt1) ? v1 : o1;
    }
  }
}

// ---------- K1: prep (blocks [0,NPREP)) + kNN 2-rows-per-wave (rest) ----------
// (256,2): VGPR cap 256 -> kregA+kregB (~95-128 live) fits WITHOUT spill.
// R17 (unbounded) allocator capped at 64 and spilled 45MB/wave. 2 blocks/CU
// = 2 waves/SIMD, each with 2 independent streams -> 4 streams/SIMD (same as
// R16's TLP) + shared x loads + interleaved sort chains.
__global__ __launch_bounds__(256, 2) void knn_prep_kernel(
    const float* __restrict__ x,  const float* __restrict__ W1,
    const float* __restrict__ W3, const float* __restrict__ W2,
    ushort* __restrict__ u, ushort* __restrict__ W3b, ushort* __restrict__ W2b,
    uint* __restrict__ g_enc, int* __restrict__ idx_out) {
  __shared__ int surv[8][256];      // 8 KB (knn path only; 2 segs per wave)
  __shared__ int cnt[8];

  if (blockIdx.x < NPREP) {         // ---- prep path ----
    int blk = blockIdx.x;
    if (blk < 1024) {
      int t = blk * 256 + threadIdx.x;      // 262144 total
      int p = t >> 3, c0 = (t & 7) * 8;
      int b = p >> 12, n = p & (NPTS - 1);
      const float* xb = x + (size_t)b * 3 * NPTS;
      float x0 = xb[n], x1 = xb[NPTS + n], x2 = xb[2 * NPTS + n];
      uint pk[4];
      #pragma unroll
      for (int j = 0; j < 8; ++j) {
        const float* w = W1 + (c0 + j) * 6;
        float v = w[3] * x0 + w[4] * x1 + w[5] * x2;
        ushort h = f2bf(v);
        if (j & 1) pk[j >> 1] |= ((uint)h << 16); else pk[j >> 1] = h;
      }
      uint4 q; q.x = pk[0]; q.y = pk[1]; q.z = pk[2]; q.w = pk[3];
      *reinterpret_cast<uint4*>(u + (size_t)p * 64 + c0) = q;
    } else if (blk < 1088) {
      int t = (blk - 1024) * 256 + threadIdx.x;   // W3 cast
      const float4* src = reinterpret_cast<const float4*>(W3 + t * 8);
      float4 f0 = src[0], f1 = src[1];
      uint4 pk;
      pk.x = (uint)f2bf(f0.x) | ((uint)f2bf(f0.y) << 16);
      pk.y = (uint)f2bf(f0.z) | ((uint)f2bf(f0.w) << 16);
      pk.z = (uint)f2bf(f1.x) | ((uint)f2bf(f1.y) << 16);
      pk.w = (uint)f2bf(f1.z) | ((uint)f2bf(f1.w) << 16);
      *reinterpret_cast<uint4*>(W3b + t * 8) = pk;
    } else if (blk < 1092) {
      int t = (blk - 1088) * 256 + threadIdx.x;   // W2 cast
      const float4* src = reinterpret_cast<const float4*>(W2 + t * 8);
      float4 f0 = src[0], f1 = src[1];
      uint4 pk;
      pk.x = (uint)f2bf(f0.x) | ((uint)f2bf(f0.y) << 16);
      pk.y = (uint)f2bf(f0.z) | ((uint)f2bf(f0.w) << 16);
      pk.z = (uint)f2bf(f1.x) | ((uint)f2bf(f1.y) << 16);
      pk.w = (uint)f2bf(f1.z) | ((uint)f2bf(f1.w) << 16);
      *reinterpret_cast<uint4*>(W2b + t * 8) = pk;
    } else {
      for (int i = threadIdx.x; i < B_SZ * 1024; i += 256) g_enc[i] = 0;
    }
    return;
  }

  // ---- knn path: wave w owns rows row0, row0+1 (same batch) ----
  const unsigned long long INFK = ~0ull;
  int w = threadIdx.x >> 6, lane = threadIdx.x & 63;
  int row0 = ((blockIdx.x - NPREP) * 4 + w) * 2;   // blocks of 8 rows, batch-aligned
  int b = row0 >> 12;
  int n0 = row0 & (NPTS - 1), n1 = n0 + 1;
  const float* xb = x + (size_t)b * 3 * NPTS;
  float q0x = xb[n0], q0y = xb[NPTS + n0], q0z = xb[2 * NPTS + n0];
  float q1x = xb[n1], q1y = xb[NPTS + n1], q1z = xb[2 * NPTS + n1];
  if (lane == 0) { cnt[2 * w] = 0; cnt[2 * w + 1] = 0; }

  const float4* X0 = reinterpret_cast<const float4*>(xb);
  const float4* X1 = reinterpret_cast<const float4*>(xb + NPTS);
  const float4* X2 = reinterpret_cast<const float4*>(xb + 2 * NPTS);

  // pass A: shared x loads, two key sets
  uint kregA[32], kregB[32];
  float bm0 = 3.0e38f, bm1 = 3.0e38f;
  #pragma unroll
  for (int i = 0; i < 16; ++i) {
    int v4 = i * 64 + lane;
    float4 a0 = X0[v4], a1 = X1[v4], a2 = X2[v4];
    float dx, dy, dz, d0, d1, d2, d3;
    // row0
    dx = a0.x - q0x; dy = a1.x - q0y; dz = a2.x - q0z; d0 = dx*dx + dy*dy + dz*dz;
    dx = a0.y - q0x; dy = a1.y - q0y; dz = a2.y - q0z; d1 = dx*dx + dy*dy + dz*dz;
    dx = a0.z - q0x; dy = a1.z - q0y; dz = a2.z - q0z; d2 = dx*dx + dy*dy + dz*dz;
    dx = a0.w - q0x; dy = a1.w - q0y; dz = a2.w - q0z; d3 = dx*dx + dy*dy + dz*dz;
    bm0 = fminf(bm0, fminf(fminf(d0, d1), fminf(d2, d3)));
    kregA[2*i]   = (__float_as_uint(d0) >> 16) | (__float_as_uint(d1) & 0xFFFF0000u);
    kregA[2*i+1] = (__float_as_uint(d2) >> 16) | (__float_as_uint(d3) & 0xFFFF0000u);
    // row1 (same a0/a1/a2)
    dx = a0.x - q1x; dy = a1.x - q1y; dz = a2.x - q1z; d0 = dx*dx + dy*dy + dz*dz;
    dx = a0.y - q1x; dy = a1.y - q1y; dz = a2.y - q1z; d1 = dx*dx + dy*dy + dz*dz;
    dx = a0.z - q1x; dy = a1.z - q1y; dz = a2.z - q1z; d2 = dx*dx + dy*dy + dz*dz;
    dx = a0.w - q1x; dy = a1.w - q1y; dz = a2.w - q1z; d3 = dx*dx + dy*dy + dz*dz;
    bm1 = fminf(bm1, fminf(fminf(d0, d1), fminf(d2, d3)));
    kregB[2*i]   = (__float_as_uint(d0) >> 16) | (__float_as_uint(d1) & 0xFFFF0000u);
    kregB[2*i+1] = (__float_as_uint(d2) >> 16) | (__float_as_uint(d3) & 0xFFFF0000u);
  }

  // thresholds (interleaved sorts)
  sortf64x2(bm0, bm1, lane);
  float T0 = __shfl(bm0, 19, 64), T1 = __shfl(bm1, 19, 64);
  uint T016 = __float_as_uint(T0) >> 16, T116 = __float_as_uint(T1) >> 16;

  // pass B: filter both rows, append to own segments
  asm volatile("s_waitcnt lgkmcnt(0)" ::: "memory");
  #pragma unroll
  for (int i = 0; i < 16; ++i) {
    int m0 = (i * 64 + lane) * 4;
    uint ka = kregA[2*i], kb = kregA[2*i+1];
    if ((ka & 0xffffu) <= T016) { int s = atomicAdd(&cnt[2*w], 1); if (s < 256) surv[2*w][s] = m0; }
    if ((ka >> 16)     <= T016) { int s = atomicAdd(&cnt[2*w], 1); if (s < 256) surv[2*w][s] = m0 + 1; }
    if ((kb & 0xffffu) <= T016) { int s = atomicAdd(&cnt[2*w], 1); if (s < 256) surv[2*w][s] = m0 + 2; }
    if ((kb >> 16)     <= T016) { int s = atomicAdd(&cnt[2*w], 1); if (s < 256) surv[2*w][s] = m0 + 3; }
    uint kc = kregB[2*i], kd = kregB[2*i+1];
    if ((kc & 0xffffu) <= T116) { int s = atomicAdd(&cnt[2*w+1], 1); if (s < 256) surv[2*w+1][s] = m0; }
    if ((kc >> 16)     <= T116) { int s = atomicAdd(&cnt[2*w+1], 1); if (s < 256) surv[2*w+1][s] = m0 + 1; }
    if ((kd & 0xffffu) <= T116) { int s = atomicAdd(&cnt[2*w+1], 1); if (s < 256) surv[2*w+1][s] = m0 + 2; }
    if ((kd >> 16)     <= T116) { int s = atomicAdd(&cnt[2*w+1], 1); if (s < 256) surv[2*w+1][s] = m0 + 3; }
  }
  asm volatile("s_waitcnt lgkmcnt(0)" ::: "memory");
  int M0 = cnt[2*w], M1 = cnt[2*w+1];

  { // interleaved chunked-bitonic fast path (discarded for any row with M>256)
    int M0c = M0 <= 256 ? M0 : 0, M1c = M1 <= 256 ? M1 : 0;
    int nch = ((M0c > M1c ? M0c : M1c) + 63) >> 6;
    unsigned long long run0 = INFK, run1 = INFK;
    for (int c = 0; c < nch; ++c) {
      int s = c * 64 + lane;
      unsigned long long v0 = INFK, v1 = INFK;
      if (s < M0c) {
        int m = surv[2*w][s];
        float dx = xb[m] - q0x, dy = xb[NPTS + m] - q0y, dz = xb[2 * NPTS + m] - q0z;
        float d = dx * dx + dy * dy + dz * dz;
        v0 = ((unsigned long long)__float_as_uint(d) << 32) | (unsigned)m;
      }
      if (s < M1c) {
        int m = surv[2*w+1][s];
        float dx = xb[m] - q1x, dy = xb[NPTS + m] - q1y, dz = xb[2 * NPTS + m] - q1z;
        float d = dx * dx + dy * dy + dz * dz;
        v1 = ((unsigned long long)__float_as_uint(d) << 32) | (unsigned)m;
      }
      sortu64x2(v0, v1, lane);
      if (c == 0) {
        run0 = v0; run1 = v1;
      } else {
        unsigned long long b0 = __shfl(v0, (19 - lane) & 63, 64);
        unsigned long long b1 = __shfl(v1, (19 - lane) & 63, 64);
        unsigned long long c0 = run0 < b0 ? run0 : b0;
        unsigned long long c1 = run1 < b1 ? run1 : b1;
        run0 = (lane < KNN) ? c0 : INFK;
        run1 = (lane < KNN) ? c1 : INFK;
        sortu64x2(run0, run1, lane);
      }
    }
    if (M0 <= 256 && lane < KNN)
      idx_out[(size_t)row0 * KNN + lane] = (int)(run0 & 0xFFFFFFFFull);
    if (M1 <= 256 && lane < KNN)
      idx_out[(size_t)(row0 + 1) * KNN + lane] = (int)(run1 & 0xFFFFFFFFull);
  }

  // pathological fallback per row (tie storms only): threshold-free extraction
  #pragma unroll 1
  for (int rr = 0; rr < 2; ++rr) {
    int M = rr ? M1 : M0;
    if (M <= 256) continue;
    float qx = rr ? q1x : q0x, qy = rr ? q1y : q0y, qz = rr ? q1z : q0z;
    int row = row0 + rr;
    unsigned long long prev = 0ull;
    for (int r = 0; r < KNN; ++r) {
      unsigned long long best = INFK;
      for (int i = 0; i < 16; ++i) {
        int v4 = i * 64 + lane;
        float4 a0 = X0[v4], a1 = X1[v4], a2 = X2[v4];
        float dx, dy, dz, d[4];
        dx = a0.x - qx; dy = a1.x - qy; dz = a2.x - qz; d[0] = dx*dx + dy*dy + dz*dz;
        dx = a0.y - qx; dy = a1.y - qy; dz = a2.y - qz; d[1] = dx*dx + dy*dy + dz*dz;
        dx = a0.z - qx; dy = a1.z - qy; dz = a2.z - qz; d[2] = dx*dx + dy*dy + dz*dz;
        dx = a0.w - qx; dy = a1.w - qy; dz = a2.w - qz; d[3] = dx*dx + dy*dy + dz*dz;
        #pragma unroll
        for (int j = 0; j < 4; ++j) {
          int m = i * 256 + lane * 4 + j;
          unsigned long long key =
              ((unsigned long long)__float_as_uint(d[j]) << 32) | (unsigned)m;
          if ((r == 0 || key > prev) && key < best) best = key;
        }
      }
      #pragma unroll
      for (int off = 32; off; off >>= 1) {
        unsigned long long o = __shfl_xor(best, off, 64);
        best = o < best ? o : best;
      }
      if (lane == 0) idx_out[(size_t)row * KNN + r] = (int)(best & 0xFFFFFFFFull);
      prev = best;
    }
  }
}

// ---------- K2: edge conv via MFMA, bf16 h128 output ----------
__global__ __launch_bounds__(256, 4) void edge_kernel(
    const float* __restrict__ x,  const float* __restrict__ W1, const float* __restrict__ b1,
    const ushort* __restrict__ W2b, const float* __restrict__ b2,
    const ushort* __restrict__ u, const int* __restrict__ idx,
    ushort* __restrict__ h128b) {
  __shared__ __align__(16) char h1s[PPB * 32 * 128];     // 32 KB
  __shared__ float vs[PPB * 64];                         // 2 KB
  __shared__ int   nbs[PPB * KNN];

  int tid = threadIdx.x, w = tid >> 6, l = tid & 63;
  int p0 = blockIdx.x * PPB;
  int b = p0 >> 12;
  const float* xb = x + (size_t)b * 3 * NPTS;

  for (int t = tid; t < PPB * 64; t += 256) {
    int p = t >> 6, c = t & 63;
    int n = (p0 + p) & (NPTS - 1);
    float x0 = xb[n], x1 = xb[NPTS + n], x2 = xb[2 * NPTS + n];
    const float* wr = W1 + c * 6;
    vs[t] = (wr[0] - wr[3]) * x0 + (wr[1] - wr[4]) * x1 + (wr[2] - wr[5]) * x2 + b1[c];
  }
  if (tid < PPB * KNN) nbs[tid] = idx[(size_t)p0 * KNN + tid];

  short8 bfr[8][2];
  #pragma unroll
  for (int nt = 0; nt < 8; ++nt) {
    #pragma unroll
    for (int ks = 0; ks < 2; ++ks) {
      bfr[nt][ks] = *(const short8*)(W2b + (nt * 16 + (l & 15)) * 64
                                         + ks * 32 + (l >> 4) * 8);
    }
  }
  __syncthreads();

  const ushort* ub = u + (((size_t)b) << 12) * 64;
  #pragma unroll
  for (int j = 0; j < 8; ++j) {
    int e_loc = j * 8 + (l >> 3);
    int p_loc = (w << 1) + (e_loc >> 5);
    int e_in = e_loc & 31;
    int e_src = (e_in < KNN) ? e_in : e_in - KNN;
    int nb = nbs[p_loc * KNN + e_src];
    int c0 = (l & 7) * 8;
    uint4 uv = *(const uint4*)(ub + (((size_t)nb) << 6) + c0);
    const float* vp = vs + p_loc * 64 + c0;
    float4 v0 = *(const float4*)vp, v1 = *(const float4*)(vp + 4);
    float h0 = fmaxf(bf2f((ushort)(uv.x & 0xffff)) + v0.x, 0.f);
    float h1 = fmaxf(bf2f((ushort)(uv.x >> 16))    + v0.y, 0.f);
    float h2 = fmaxf(bf2f((ushort)(uv.y & 0xffff)) + v0.z, 0.f);
    float h3 = fmaxf(bf2f((ushort)(uv.y >> 16))    + v0.w, 0.f);
    float h4 = fmaxf(bf2f((ushort)(uv.z & 0xffff)) + v1.x, 0.f);
    float h5 = fmaxf(bf2f((ushort)(uv.z >> 16))    + v1.y, 0.f);
    float h6 = fmaxf(bf2f((ushort)(uv.w & 0xffff)) + v1.z, 0.f);
    float h7 = fmaxf(bf2f((ushort)(uv.w >> 16))    + v1.w, 0.f);
    uint4 pk;
    pk.x = (uint)f2bf(h0) | ((uint)f2bf(h1) << 16);
    pk.y = (uint)f2bf(h2) | ((uint)f2bf(h3) << 16);
    pk.z = (uint)f2bf(h4) | ((uint)f2bf(h5) << 16);
    pk.w = (uint)f2bf(h6) | ((uint)f2bf(h7) << 16);
    int row = (w << 6) + e_loc;
    int byte = (row * 128 + c0 * 2) ^ ((row & 7) << 4);
    *(uint4*)(h1s + byte) = pk;
  }
  __syncthreads();

  float bias0 = b2[l], bias1 = b2[64 + l];

  #pragma unroll
  for (int pt = 0; pt < 2; ++pt) {
    int rbase = (w << 6) + (pt << 5);
    short8 a[2][2];
    #pragma unroll
    for (int m = 0; m < 2; ++m) {
      #pragma unroll
      for (int ks = 0; ks < 2; ++ks) {
        int row = rbase + m * 16 + (l & 15);
        int byte = (row * 128 + ks * 64 + (l >> 4) * 16) ^ ((row & 7) << 4);
        a[m][ks] = *(const short8*)(h1s + byte);
      }
    }
    float r03 = 0.f, r47 = 0.f;
    #pragma unroll
    for (int nt = 0; nt < 8; ++nt) {
      f32x4 acc0 = {0.f, 0.f, 0.f, 0.f}, acc1 = {0.f, 0.f, 0.f, 0.f};
      acc0 = __builtin_amdgcn_mfma_f32_16x16x32_bf16(a[0][0], bfr[nt][0], acc0, 0, 0, 0);
      acc0 = __builtin_amdgcn_mfma_f32_16x16x32_bf16(a[0][1], bfr[nt][1], acc0, 0, 0, 0);
      acc1 = __builtin_amdgcn_mfma_f32_16x16x32_bf16(a[1][0], bfr[nt][0], acc1, 0, 0, 0);
      acc1 = __builtin_amdgcn_mfma_f32_16x16x32_bf16(a[1][1], bfr[nt][1], acc1, 0, 0, 0);
      float m0 = fmaxf(fmaxf(fmaxf(acc0[0], acc1[0]), fmaxf(acc0[1], acc1[1])),
                       fmaxf(fmaxf(acc0[2], acc1[2]), fmaxf(acc0[3], acc1[3])));
      m0 = fmaxf(m0, __shfl_xor(m0, 16, 64));
      m0 = fmaxf(m0, __shfl_xor(m0, 32, 64));
      if ((l >> 4) == (nt & 3)) { if (nt < 4) r03 = m0; else r47 = m0; }
    }
    int pg = p0 + (w << 1) + pt;
    h128b[(size_t)pg * 128 + l]      = f2bf(fmaxf(r03 + bias0, 0.f));
    h128b[(size_t)pg * 128 + 64 + l] = f2bf(fmaxf(r47 + bias1, 0.f));
  }
}

// ---------- K3: inter via MFMA, 64-point chunks, atomicMax into encoded g ----------
__global__ __launch_bounds__(256, 2) void inter_kernel(
    const ushort* __restrict__ h128b, const ushort* __restrict__ W3b,
    uint* __restrict__ g_enc) {
  __shared__ __align__(16) char as_[64 * 256];   // 16 KB
  int tid = threadIdx.x, w = tid >> 6, l = tid & 63;
  int chunk = blockIdx.x;                         // 0..511 (64 points each)
  const ushort* hp = h128b + (size_t)chunk * 64 * 128;

  { // stage: thread t -> row t>>2, quarter t&3 (64B = 4 uint4)
    int row = tid >> 2, q = tid & 3;
    const uint4* src = reinterpret_cast<const uint4*>(hp + row * 128 + q * 32);
    int sw = (row & 7) << 4;
    int base = row * 256 + q * 64;
    #pragma unroll
    for (int k = 0; k < 4; ++k)
      *(uint4*)(as_ + ((base + k * 16) ^ sw)) = src[k];
  }
  __syncthreads();

  short8 a[4][4];
  #pragma unroll
  for (int m = 0; m < 4; ++m) {
    #pragma unroll
    for (int ks = 0; ks < 4; ++ks) {
      int row = m * 16 + (l & 15);
      int byte = (row * 256 + ks * 64 + (l >> 4) * 16) ^ ((row & 7) << 4);
      a[m][ks] = *(const short8*)(as_ + byte);
    }
  }

  const ushort* wb = W3b + (size_t)(w * 256) * 128;
  float res[4];
  #pragma unroll
  for (int nt = 0; nt < 16; ++nt) {
    f32x4 acc0 = {0.f,0.f,0.f,0.f}, acc1 = {0.f,0.f,0.f,0.f};
    f32x4 acc2 = {0.f,0.f,0.f,0.f}, acc3 = {0.f,0.f,0.f,0.f};
    #pragma unroll
    for (int ks = 0; ks < 4; ++ks) {
      short8 bf = *(const short8*)(wb + (size_t)(nt * 16 + (l & 15)) * 128
                                      + ks * 32 + (l >> 4) * 8);
      acc0 = __builtin_amdgcn_mfma_f32_16x16x32_bf16(a[0][ks], bf, acc0, 0, 0, 0);
      acc1 = __builtin_amdgcn_mfma_f32_16x16x32_bf16(a[1][ks], bf, acc1, 0, 0, 0);
      acc2 = __builtin_amdgcn_mfma_f32_16x16x32_bf16(a[2][ks], bf, acc2, 0, 0, 0);
      acc3 = __builtin_amdgcn_mfma_f32_16x16x32_bf16(a[3][ks], bf, acc3, 0, 0, 0);
    }
    float m01 = fmaxf(fmaxf(fmaxf(acc0[0], acc1[0]), fmaxf(acc0[1], acc1[1])),
                      fmaxf(fmaxf(acc0[2], acc1[2]), fmaxf(acc0[3], acc1[3])));
    float m23 = fmaxf(fmaxf(fmaxf(acc2[0], acc3[0]), fmaxf(acc2[1], acc3[1])),
                      fmaxf(fmaxf(acc2[2], acc3[2]), fmaxf(acc2[3], acc3[3])));
    float m0 = fmaxf(m01, m23);
    m0 = fmaxf(m0, __shfl_xor(m0, 16, 64));
    m0 = fmaxf(m0, __shfl_xor(m0, 32, 64));
    if ((l >> 4) == (nt & 3)) res[nt >> 2] = m0;
  }
  uint* ge = g_enc + (size_t)(chunk >> 6) * 1024 + w * 256;
  #pragma unroll
  for (int g = 0; g < 4; ++g) atomicMax(ge + g * 64 + l, fenc(res[g]));
}

// ---------- K4/5/6: small FCs, one wave per output ----------
__global__ __launch_bounds__(64) void fc_kernel(const float* __restrict__ in,
                                                const uint* __restrict__ enc,
                                                const float* __restrict__ pre_b,
                                                const float* __restrict__ W,
                                                const float* __restrict__ bias,
                                                float* __restrict__ out,
                                                int in_dim, int out_dim, int mode) {
  int blk = blockIdx.x;
  int b = blk / out_dim, o = blk % out_dim;
  int lane = threadIdx.x;
  const float* w = W + (size_t)o * in_dim;
  float s = 0.f;
  for (int c = lane; c < in_dim; c += 64) {
    float v;
    if (mode == 2) v = fmaxf(fdec(enc[(size_t)b * in_dim + c]) + pre_b[c], 0.f);
    else           v = in[(size_t)b * in_dim + c];
    s += v * w[c];
  }
  #pragma unroll
  for (int off = 32; off; off >>= 1) s += __shfl_down(s, off);
  if (lane == 0) {
    float r = s + bias[o];
    if (mode != 1) r = fmaxf(r, 0.0f);
    else if (o == 0 || o == 4 || o == 8) r += 1.0f;
    out[blk] = r;
  }
}

extern "C" void kernel_launch(void* const* d_in, const int* in_sizes, int n_in,
                              void* d_out, int out_size, void* d_ws, size_t ws_size,
                              hipStream_t stream) {
  const float* x  = (const float*)d_in[0];
  const float* W1 = (const float*)d_in[1];
  const float* b1 = (const float*)d_in[2];
  const float* W2 = (const float*)d_in[3];
  const float* b2 = (const float*)d_in[4];
  const float* W3 = (const float*)d_in[5];
  const float* b3 = (const float*)d_in[6];
  const float* W4 = (const float*)d_in[7];
  const float* b4 = (const float*)d_in[8];
  const float* W5 = (const float*)d_in[9];
  const float* b5 = (const float*)d_in[10];
  const float* W6 = (const float*)d_in[11];
  const float* b6 = (const float*)d_in[12];
  float* out = (float*)d_out;

  char* ws = (char*)d_ws;
  ushort* u_bf  = (ushort*)(ws);                              // [0,4M)
  int*    idxb  = (int*)  (ws + (8u  << 20));                 // [8,10.5M)
  ushort* h128b = (ushort*)(ws + (11u << 20));                // [11,19M) bf16
  ushort* W3b   = (ushort*)(ws + (27u << 20));                // 256 KB
  ushort* W2b   = (ushort*)(ws + (27u << 20) + (256u << 10)); // 16 KB
  uint*   g_enc = (uint*) (ws + (5u  << 20));                 // 32 KB
  float*  g4    = (float*)(ws + (6u  << 20));
  float*  g5    = (float*)(ws + (7u  << 20));

  hipLaunchKernelGGL(knn_prep_kernel, dim3(NPREP + 4096), dim3(256), 0, stream,
                     x, W1, W3, W2, u_bf, W3b, W2b, g_enc, idxb);
  hipLaunchKernelGGL(edge_kernel, dim3(NTOT / PPB), dim3(256), 0, stream,
                     x, W1, b1, W2b, b2, u_bf, idxb, h128b);
  hipLaunchKernelGGL(inter_kernel, dim3(512), dim3(256), 0, stream, h128b, W3b, g_enc);
  hipLaunchKernelGGL(fc_kernel, dim3(B_SZ * 512), dim3(64), 0, stream,
                     nullptr, g_enc, b3, W4, b4, g4, 1024, 512, 2);
  hipLaunchKernelGGL(fc_kernel, dim3(B_SZ * 256), dim3(64), 0, stream,
                     g4, nullptr, nullptr, W5, b5, g5, 512, 256, 0);
  hipLaunchKernelGGL(fc_kernel, dim3(B_SZ * 9),   dim3(64), 0, stream,
                     g5, nullptr, nullptr, W6, b6, out, 256, 9, 1);
}

// Round 19
// 167.285 us; speedup vs baseline: 1.1781x; 1.1115x over previous
//
#include <hip/hip_runtime.h>
#include <hip/hip_bf16.h>
#include <cstdint>

#define B_SZ 8
#define NPTS 4096
#define KNN  20
#define NTOT (B_SZ * NPTS)   // 32768 points
#define PPB  8               // points per edge-kernel block
#define NPREP 1093           // prep blocks (1024 u + 64 W3 + 4 W2 + 1 gzero)

typedef unsigned int uint;
typedef unsigned short ushort;
using short8 = __attribute__((ext_vector_type(8))) short;
using f32x4  = __attribute__((ext_vector_type(4))) float;

__device__ __forceinline__ ushort f2bf(float f) {
  uint u = __float_as_uint(f);
  u += 0x7fff + ((u >> 16) & 1);          // RNE
  return (ushort)(u >> 16);
}
__device__ __forceinline__ float bf2f(ushort h) {
  return __uint_as_float(((uint)h) << 16);
}
// order-monotone float<->uint encoding (exact; for atomicMax-based max)
__device__ __forceinline__ uint fenc(float f) {
  uint u = __float_as_uint(f);
  return (u & 0x80000000u) ? ~u : (u | 0x80000000u);
}
__device__ __forceinline__ float fdec(uint e) {
  uint u = (e & 0x80000000u) ? (e & 0x7fffffffu) : ~e;
  return __uint_as_float(u);
}

// ---------- kNN helpers ----------
__device__ __forceinline__ void sortf64(float& v, int lane) {
  #pragma unroll
  for (int k = 2; k <= 64; k <<= 1) {
    #pragma unroll
    for (int j = k >> 1; j > 0; j >>= 1) {
      float o = __shfl_xor(v, j, 64);
      bool keepmin = (((lane & k) == 0) == ((lane & j) == 0));
      bool lt = v < o;
      v = (keepmin == lt) ? v : o;
    }
  }
}

__device__ __forceinline__ void sortu64(unsigned long long& v, int lane) {
  #pragma unroll
  for (int k = 2; k <= 64; k <<= 1) {
    #pragma unroll
    for (int j = k >> 1; j > 0; j >>= 1) {
      unsigned long long o = __shfl_xor(v, j, 64);
      bool keepmin = (((lane & k) == 0) == ((lane & j) == 0));
      bool lt = v < o;
      v = (keepmin == lt) ? v : o;
    }
  }
}

// ---------- K1: prep (blocks [0,NPREP), runs first) + kNN (rest) ----------
// Final config (R16, best measured 167.97us total). Lever space mapped:
// occupancy pinned at ~16 waves/CU for any hint (R14/15/16); VGPR floor 48,
// spill cliff below (R9/15/17); ILP 2-rows/wave negative (R18); batched
// atomics neutral (R10); 2-wave split negative (R11). Structural floor.
__global__ void knn_prep_kernel(
    const float* __restrict__ x,  const float* __restrict__ W1,
    const float* __restrict__ W3, const float* __restrict__ W2,
    ushort* __restrict__ u, ushort* __restrict__ W3b, ushort* __restrict__ W2b,
    uint* __restrict__ g_enc, int* __restrict__ idx_out) {
  __shared__ int surv[4][256];      // 4 KB (knn path only)
  __shared__ int cnt[4];

  if (blockIdx.x < NPREP) {         // ---- prep path (fast blocks, run first) ----
    int blk = blockIdx.x;
    if (blk < 1024) {
      int t = blk * 256 + threadIdx.x;      // 262144 total
      int p = t >> 3, c0 = (t & 7) * 8;
      int b = p >> 12, n = p & (NPTS - 1);
      const float* xb = x + (size_t)b * 3 * NPTS;
      float x0 = xb[n], x1 = xb[NPTS + n], x2 = xb[2 * NPTS + n];
      uint pk[4];
      #pragma unroll
      for (int j = 0; j < 8; ++j) {
        const float* w = W1 + (c0 + j) * 6;
        float v = w[3] * x0 + w[4] * x1 + w[5] * x2;
        ushort h = f2bf(v);
        if (j & 1) pk[j >> 1] |= ((uint)h << 16); else pk[j >> 1] = h;
      }
      uint4 q; q.x = pk[0]; q.y = pk[1]; q.z = pk[2]; q.w = pk[3];
      *reinterpret_cast<uint4*>(u + (size_t)p * 64 + c0) = q;
    } else if (blk < 1088) {
      int t = (blk - 1024) * 256 + threadIdx.x;   // W3 cast
      const float4* src = reinterpret_cast<const float4*>(W3 + t * 8);
      float4 f0 = src[0], f1 = src[1];
      uint4 pk;
      pk.x = (uint)f2bf(f0.x) | ((uint)f2bf(f0.y) << 16);
      pk.y = (uint)f2bf(f0.z) | ((uint)f2bf(f0.w) << 16);
      pk.z = (uint)f2bf(f1.x) | ((uint)f2bf(f1.y) << 16);
      pk.w = (uint)f2bf(f1.z) | ((uint)f2bf(f1.w) << 16);
      *reinterpret_cast<uint4*>(W3b + t * 8) = pk;
    } else if (blk < 1092) {
      int t = (blk - 1088) * 256 + threadIdx.x;   // W2 cast
      const float4* src = reinterpret_cast<const float4*>(W2 + t * 8);
      float4 f0 = src[0], f1 = src[1];
      uint4 pk;
      pk.x = (uint)f2bf(f0.x) | ((uint)f2bf(f0.y) << 16);
      pk.y = (uint)f2bf(f0.z) | ((uint)f2bf(f0.w) << 16);
      pk.z = (uint)f2bf(f1.x) | ((uint)f2bf(f1.y) << 16);
      pk.w = (uint)f2bf(f1.z) | ((uint)f2bf(f1.w) << 16);
      *reinterpret_cast<uint4*>(W2b + t * 8) = pk;
    } else {
      for (int i = threadIdx.x; i < B_SZ * 1024; i += 256) g_enc[i] = 0;
    }
    return;
  }

  // ---- knn path (R8 structure; VGPR 48, no spill) ----
  const unsigned long long INFK = ~0ull;
  int w = threadIdx.x >> 6, lane = threadIdx.x & 63;
  int row = (blockIdx.x - NPREP) * 4 + w;
  int b = row >> 12, n = row & (NPTS - 1);
  const float* xb = x + (size_t)b * 3 * NPTS;
  float qx = xb[n], qy = xb[NPTS + n], qz = xb[2 * NPTS + n];
  if (lane == 0) cnt[w] = 0;

  const float4* X0 = reinterpret_cast<const float4*>(xb);
  const float4* X1 = reinterpret_cast<const float4*>(xb + NPTS);
  const float4* X2 = reinterpret_cast<const float4*>(xb + 2 * NPTS);

  uint kreg[32];
  float bm = 3.0e38f;
  #pragma unroll
  for (int i = 0; i < 16; ++i) {
    int v4 = i * 64 + lane;
    float4 a0 = X0[v4], a1 = X1[v4], a2 = X2[v4];
    float dx, dy, dz, d0, d1, d2, d3;
    dx = a0.x - qx; dy = a1.x - qy; dz = a2.x - qz; d0 = dx*dx + dy*dy + dz*dz;
    dx = a0.y - qx; dy = a1.y - qy; dz = a2.y - qz; d1 = dx*dx + dy*dy + dz*dz;
    dx = a0.z - qx; dy = a1.z - qy; dz = a2.z - qz; d2 = dx*dx + dy*dy + dz*dz;
    dx = a0.w - qx; dy = a1.w - qy; dz = a2.w - qz; d3 = dx*dx + dy*dy + dz*dz;
    bm = fminf(bm, fminf(fminf(d0, d1), fminf(d2, d3)));
    kreg[2*i]   = (__float_as_uint(d0) >> 16) | (__float_as_uint(d1) & 0xFFFF0000u);
    kreg[2*i+1] = (__float_as_uint(d2) >> 16) | (__float_as_uint(d3) & 0xFFFF0000u);
  }

  sortf64(bm, lane);
  float T = __shfl(bm, 19, 64);
  uint T16 = __float_as_uint(T) >> 16;

  asm volatile("s_waitcnt lgkmcnt(0)" ::: "memory");
  #pragma unroll
  for (int i = 0; i < 16; ++i) {
    uint ka = kreg[2*i], kb = kreg[2*i+1];
    int m0 = (i * 64 + lane) * 4;
    if ((ka & 0xffffu) <= T16) { int s = atomicAdd(&cnt[w], 1); if (s < 256) surv[w][s] = m0; }
    if ((ka >> 16)     <= T16) { int s = atomicAdd(&cnt[w], 1); if (s < 256) surv[w][s] = m0 + 1; }
    if ((kb & 0xffffu) <= T16) { int s = atomicAdd(&cnt[w], 1); if (s < 256) surv[w][s] = m0 + 2; }
    if ((kb >> 16)     <= T16) { int s = atomicAdd(&cnt[w], 1); if (s < 256) surv[w][s] = m0 + 3; }
  }
  asm volatile("s_waitcnt lgkmcnt(0)" ::: "memory");
  int M = cnt[w];

  if (M <= 256) {
    unsigned long long run = INFK;
    int nch = (M + 63) >> 6;
    for (int c = 0; c < nch; ++c) {
      int s = c * 64 + lane;
      unsigned long long v = INFK;
      if (s < M) {
        int m = surv[w][s];
        float dx = xb[m] - qx, dy = xb[NPTS + m] - qy, dz = xb[2 * NPTS + m] - qz;
        float d = dx * dx + dy * dy + dz * dz;
        v = ((unsigned long long)__float_as_uint(d) << 32) | (unsigned)m;
      }
      sortu64(v, lane);
      if (c == 0) {
        run = v;
      } else {
        unsigned long long b19 = __shfl(v, (19 - lane) & 63, 64);
        unsigned long long cand = run < b19 ? run : b19;
        run = (lane < KNN) ? cand : INFK;
        sortu64(run, lane);
      }
    }
    if (lane < KNN) idx_out[(size_t)row * KNN + lane] = (int)(run & 0xFFFFFFFFull);
  } else {
    unsigned long long prev = 0ull;
    for (int r = 0; r < KNN; ++r) {
      unsigned long long best = INFK;
      for (int i = 0; i < 16; ++i) {
        int v4 = i * 64 + lane;
        float4 a0 = X0[v4], a1 = X1[v4], a2 = X2[v4];
        float dx, dy, dz, d[4];
        dx = a0.x - qx; dy = a1.x - qy; dz = a2.x - qz; d[0] = dx*dx + dy*dy + dz*dz;
        dx = a0.y - qx; dy = a1.y - qy; dz = a2.y - qz; d[1] = dx*dx + dy*dy + dz*dz;
        dx = a0.z - qx; dy = a1.z - qy; dz = a2.z - qz; d[2] = dx*dx + dy*dy + dz*dz;
        dx = a0.w - qx; dy = a1.w - qy; dz = a2.w - qz; d[3] = dx*dx + dy*dy + dz*dz;
        #pragma unroll
        for (int j = 0; j < 4; ++j) {
          int m = i * 256 + lane * 4 + j;
          unsigned long long key =
              ((unsigned long long)__float_as_uint(d[j]) << 32) | (unsigned)m;
          if ((r == 0 || key > prev) && key < best) best = key;
        }
      }
      #pragma unroll
      for (int off = 32; off; off >>= 1) {
        unsigned long long o = __shfl_xor(best, off, 64);
        best = o < best ? o : best;
      }
      if (lane == 0) idx_out[(size_t)row * KNN + r] = (int)(best & 0xFFFFFFFFull);
      prev = best;
    }
  }
}

// ---------- K2: edge conv via MFMA, bf16 h128 output ----------
__global__ __launch_bounds__(256, 4) void edge_kernel(
    const float* __restrict__ x,  const float* __restrict__ W1, const float* __restrict__ b1,
    const ushort* __restrict__ W2b, const float* __restrict__ b2,
    const ushort* __restrict__ u, const int* __restrict__ idx,
    ushort* __restrict__ h128b) {
  __shared__ __align__(16) char h1s[PPB * 32 * 128];     // 32 KB
  __shared__ float vs[PPB * 64];                         // 2 KB
  __shared__ int   nbs[PPB * KNN];

  int tid = threadIdx.x, w = tid >> 6, l = tid & 63;
  int p0 = blockIdx.x * PPB;
  int b = p0 >> 12;
  const float* xb = x + (size_t)b * 3 * NPTS;

  for (int t = tid; t < PPB * 64; t += 256) {
    int p = t >> 6, c = t & 63;
    int n = (p0 + p) & (NPTS - 1);
    float x0 = xb[n], x1 = xb[NPTS + n], x2 = xb[2 * NPTS + n];
    const float* wr = W1 + c * 6;
    vs[t] = (wr[0] - wr[3]) * x0 + (wr[1] - wr[4]) * x1 + (wr[2] - wr[5]) * x2 + b1[c];
  }
  if (tid < PPB * KNN) nbs[tid] = idx[(size_t)p0 * KNN + tid];

  short8 bfr[8][2];
  #pragma unroll
  for (int nt = 0; nt < 8; ++nt) {
    #pragma unroll
    for (int ks = 0; ks < 2; ++ks) {
      bfr[nt][ks] = *(const short8*)(W2b + (nt * 16 + (l & 15)) * 64
                                         + ks * 32 + (l >> 4) * 8);
    }
  }
  __syncthreads();

  const ushort* ub = u + (((size_t)b) << 12) * 64;
  #pragma unroll
  for (int j = 0; j < 8; ++j) {
    int e_loc = j * 8 + (l >> 3);
    int p_loc = (w << 1) + (e_loc >> 5);
    int e_in = e_loc & 31;
    int e_src = (e_in < KNN) ? e_in : e_in - KNN;
    int nb = nbs[p_loc * KNN + e_src];
    int c0 = (l & 7) * 8;
    uint4 uv = *(const uint4*)(ub + (((size_t)nb) << 6) + c0);
    const float* vp = vs + p_loc * 64 + c0;
    float4 v0 = *(const float4*)vp, v1 = *(const float4*)(vp + 4);
    float h0 = fmaxf(bf2f((ushort)(uv.x & 0xffff)) + v0.x, 0.f);
    float h1 = fmaxf(bf2f((ushort)(uv.x >> 16))    + v0.y, 0.f);
    float h2 = fmaxf(bf2f((ushort)(uv.y & 0xffff)) + v0.z, 0.f);
    float h3 = fmaxf(bf2f((ushort)(uv.y >> 16))    + v0.w, 0.f);
    float h4 = fmaxf(bf2f((ushort)(uv.z & 0xffff)) + v1.x, 0.f);
    float h5 = fmaxf(bf2f((ushort)(uv.z >> 16))    + v1.y, 0.f);
    float h6 = fmaxf(bf2f((ushort)(uv.w & 0xffff)) + v1.z, 0.f);
    float h7 = fmaxf(bf2f((ushort)(uv.w >> 16))    + v1.w, 0.f);
    uint4 pk;
    pk.x = (uint)f2bf(h0) | ((uint)f2bf(h1) << 16);
    pk.y = (uint)f2bf(h2) | ((uint)f2bf(h3) << 16);
    pk.z = (uint)f2bf(h4) | ((uint)f2bf(h5) << 16);
    pk.w = (uint)f2bf(h6) | ((uint)f2bf(h7) << 16);
    int row = (w << 6) + e_loc;
    int byte = (row * 128 + c0 * 2) ^ ((row & 7) << 4);
    *(uint4*)(h1s + byte) = pk;
  }
  __syncthreads();

  float bias0 = b2[l], bias1 = b2[64 + l];

  #pragma unroll
  for (int pt = 0; pt < 2; ++pt) {
    int rbase = (w << 6) + (pt << 5);
    short8 a[2][2];
    #pragma unroll
    for (int m = 0; m < 2; ++m) {
      #pragma unroll
      for (int ks = 0; ks < 2; ++ks) {
        int row = rbase + m * 16 + (l & 15);
        int byte = (row * 128 + ks * 64 + (l >> 4) * 16) ^ ((row & 7) << 4);
        a[m][ks] = *(const short8*)(h1s + byte);
      }
    }
    float r03 = 0.f, r47 = 0.f;
    #pragma unroll
    for (int nt = 0; nt < 8; ++nt) {
      f32x4 acc0 = {0.f, 0.f, 0.f, 0.f}, acc1 = {0.f, 0.f, 0.f, 0.f};
      acc0 = __builtin_amdgcn_mfma_f32_16x16x32_bf16(a[0][0], bfr[nt][0], acc0, 0, 0, 0);
      acc0 = __builtin_amdgcn_mfma_f32_16x16x32_bf16(a[0][1], bfr[nt][1], acc0, 0, 0, 0);
      acc1 = __builtin_amdgcn_mfma_f32_16x16x32_bf16(a[1][0], bfr[nt][0], acc1, 0, 0, 0);
      acc1 = __builtin_amdgcn_mfma_f32_16x16x32_bf16(a[1][1], bfr[nt][1], acc1, 0, 0, 0);
      float m0 = fmaxf(fmaxf(fmaxf(acc0[0], acc1[0]), fmaxf(acc0[1], acc1[1])),
                       fmaxf(fmaxf(acc0[2], acc1[2]), fmaxf(acc0[3], acc1[3])));
      m0 = fmaxf(m0, __shfl_xor(m0, 16, 64));
      m0 = fmaxf(m0, __shfl_xor(m0, 32, 64));
      if ((l >> 4) == (nt & 3)) { if (nt < 4) r03 = m0; else r47 = m0; }
    }
    int pg = p0 + (w << 1) + pt;
    h128b[(size_t)pg * 128 + l]      = f2bf(fmaxf(r03 + bias0, 0.f));
    h128b[(size_t)pg * 128 + 64 + l] = f2bf(fmaxf(r47 + bias1, 0.f));
  }
}

// ---------- K3: inter via MFMA, 64-point chunks, atomicMax into encoded g ----------
__global__ __launch_bounds__(256, 2) void inter_kernel(
    const ushort* __restrict__ h128b, const ushort* __restrict__ W3b,
    uint* __restrict__ g_enc) {
  __shared__ __align__(16) char as_[64 * 256];   // 16 KB
  int tid = threadIdx.x, w = tid >> 6, l = tid & 63;
  int chunk = blockIdx.x;                         // 0..511 (64 points each)
  const ushort* hp = h128b + (size_t)chunk * 64 * 128;

  { // stage: thread t -> row t>>2, quarter t&3 (64B = 4 uint4)
    int row = tid >> 2, q = tid & 3;
    const uint4* src = reinterpret_cast<const uint4*>(hp + row * 128 + q * 32);
    int sw = (row & 7) << 4;
    int base = row * 256 + q * 64;
    #pragma unroll
    for (int k = 0; k < 4; ++k)
      *(uint4*)(as_ + ((base + k * 16) ^ sw)) = src[k];
  }
  __syncthreads();

  short8 a[4][4];
  #pragma unroll
  for (int m = 0; m < 4; ++m) {
    #pragma unroll
    for (int ks = 0; ks < 4; ++ks) {
      int row = m * 16 + (l & 15);
      int byte = (row * 256 + ks * 64 + (l >> 4) * 16) ^ ((row & 7) << 4);
      a[m][ks] = *(const short8*)(as_ + byte);
    }
  }

  const ushort* wb = W3b + (size_t)(w * 256) * 128;
  float res[4];
  #pragma unroll
  for (int nt = 0; nt < 16; ++nt) {
    f32x4 acc0 = {0.f,0.f,0.f,0.f}, acc1 = {0.f,0.f,0.f,0.f};
    f32x4 acc2 = {0.f,0.f,0.f,0.f}, acc3 = {0.f,0.f,0.f,0.f};
    #pragma unroll
    for (int ks = 0; ks < 4; ++ks) {
      short8 bf = *(const short8*)(wb + (size_t)(nt * 16 + (l & 15)) * 128
                                      + ks * 32 + (l >> 4) * 8);
      acc0 = __builtin_amdgcn_mfma_f32_16x16x32_bf16(a[0][ks], bf, acc0, 0, 0, 0);
      acc1 = __builtin_amdgcn_mfma_f32_16x16x32_bf16(a[1][ks], bf, acc1, 0, 0, 0);
      acc2 = __builtin_amdgcn_mfma_f32_16x16x32_bf16(a[2][ks], bf, acc2, 0, 0, 0);
      acc3 = __builtin_amdgcn_mfma_f32_16x16x32_bf16(a[3][ks], bf, acc3, 0, 0, 0);
    }
    float m01 = fmaxf(fmaxf(fmaxf(acc0[0], acc1[0]), fmaxf(acc0[1], acc1[1])),
                      fmaxf(fmaxf(acc0[2], acc1[2]), fmaxf(acc0[3], acc1[3])));
    float m23 = fmaxf(fmaxf(fmaxf(acc2[0], acc3[0]), fmaxf(acc2[1], acc3[1])),
                      fmaxf(fmaxf(acc2[2], acc3[2]), fmaxf(acc2[3], acc3[3])));
    float m0 = fmaxf(m01, m23);
    m0 = fmaxf(m0, __shfl_xor(m0, 16, 64));
    m0 = fmaxf(m0, __shfl_xor(m0, 32, 64));
    if ((l >> 4) == (nt & 3)) res[nt >> 2] = m0;
  }
  uint* ge = g_enc + (size_t)(chunk >> 6) * 1024 + w * 256;
  #pragma unroll
  for (int g = 0; g < 4; ++g) atomicMax(ge + g * 64 + l, fenc(res[g]));
}

// ---------- K4/5/6: small FCs, one wave per output ----------
__global__ __launch_bounds__(64) void fc_kernel(const float* __restrict__ in,
                                                const uint* __restrict__ enc,
                                                const float* __restrict__ pre_b,
                                                const float* __restrict__ W,
                                                const float* __restrict__ bias,
                                                float* __restrict__ out,
                                                int in_dim, int out_dim, int mode) {
  int blk = blockIdx.x;
  int b = blk / out_dim, o = blk % out_dim;
  int lane = threadIdx.x;
  const float* w = W + (size_t)o * in_dim;
  float s = 0.f;
  for (int c = lane; c < in_dim; c += 64) {
    float v;
    if (mode == 2) v = fmaxf(fdec(enc[(size_t)b * in_dim + c]) + pre_b[c], 0.f);
    else           v = in[(size_t)b * in_dim + c];
    s += v * w[c];
  }
  #pragma unroll
  for (int off = 32; off; off >>= 1) s += __shfl_down(s, off);
  if (lane == 0) {
    float r = s + bias[o];
    if (mode != 1) r = fmaxf(r, 0.0f);
    else if (o == 0 || o == 4 || o == 8) r += 1.0f;
    out[blk] = r;
  }
}

extern "C" void kernel_launch(void* const* d_in, const int* in_sizes, int n_in,
                              void* d_out, int out_size, void* d_ws, size_t ws_size,
                              hipStream_t stream) {
  const float* x  = (const float*)d_in[0];
  const float* W1 = (const float*)d_in[1];
  const float* b1 = (const float*)d_in[2];
  const float* W2 = (const float*)d_in[3];
  const float* b2 = (const float*)d_in[4];
  const float* W3 = (const float*)d_in[5];
  const float* b3 = (const float*)d_in[6];
  const float* W4 = (const float*)d_in[7];
  const float* b4 = (const float*)d_in[8];
  const float* W5 = (const float*)d_in[9];
  const float* b5 = (const float*)d_in[10];
  const float* W6 = (const float*)d_in[11];
  const float* b6 = (const float*)d_in[12];
  float* out = (float*)d_out;

  char* ws = (char*)d_ws;
  ushort* u_bf  = (ushort*)(ws);                              // [0,4M)
  int*    idxb  = (int*)  (ws + (8u  << 20));                 // [8,10.5M)
  ushort* h128b = (ushort*)(ws + (11u << 20));                // [11,19M) bf16
  ushort* W3b   = (ushort*)(ws + (27u << 20));                // 256 KB
  ushort* W2b   = (ushort*)(ws + (27u << 20) + (256u << 10)); // 16 KB
  uint*   g_enc = (uint*) (ws + (5u  << 20));                 // 32 KB
  float*  g4    = (float*)(ws + (6u  << 20));
  float*  g5    = (float*)(ws + (7u  << 20));

  hipLaunchKernelGGL(knn_prep_kernel, dim3(NPREP + 8192), dim3(256), 0, stream,
                     x, W1, W3, W2, u_bf, W3b, W2b, g_enc, idxb);
  hipLaunchKernelGGL(edge_kernel, dim3(NTOT / PPB), dim3(256), 0, stream,
                     x, W1, b1, W2b, b2, u_bf, idxb, h128b);
  hipLaunchKernelGGL(inter_kernel, dim3(512), dim3(256), 0, stream, h128b, W3b, g_enc);
  hipLaunchKernelGGL(fc_kernel, dim3(B_SZ * 512), dim3(64), 0, stream,
                     nullptr, g_enc, b3, W4, b4, g4, 1024, 512, 2);
  hipLaunchKernelGGL(fc_kernel, dim3(B_SZ * 256), dim3(64), 0, stream,
                     g4, nullptr, nullptr, W5, b5, g5, 512, 256, 0);
  hipLaunchKernelGGL(fc_kernel, dim3(B_SZ * 9),   dim3(64), 0, stream,
                     g5, nullptr, nullptr, W6, b6, out, 256, 9, 1);
}